// Round 14
// baseline (534.054 us; speedup 1.0000x reference)
//
#include <hip/hip_runtime.h>
#include <cstdint>
#include <cstddef>

// x[B=512, L=32, H=32, D=128]; per (l,h): Linear(128->128) -> GELU -> Linear(128->128)
// R14: barrier-free independent waves. One block per lh (keeps R9's L3 credit).
// W1+W2 staged ONCE to LDS as bf16 MFMA fragments (64 KB, read-only after one
// prologue barrier). Each wave owns 128 batch rows, 8 tiles x 16 rows, with
// wave-private H scratch (4 KB) -> ZERO barriers in the tile loop; 8 fully
// independent wave-streams/CU (vs R9's 2 lockstepped blocks). x is loaded
// direct-to-VGPR with FULL-TILE prefetch distance (fixes R12's shallow lookahead).
#define LH      1024
#define Dd      128
#define BT      16            // rows per tile per wave
#define NTILE   8             // 128 rows per wave / 16
#define XSTRIDE (LH * Dd)

typedef __attribute__((ext_vector_type(8))) short bf16x8;
typedef __attribute__((ext_vector_type(4))) float f32x4;

static __device__ __forceinline__ short f2bf(float f) {
  return __builtin_bit_cast(short, (__bf16)f);
}

// tanh-form GELU as one sigmoid; |diff| vs erf-gelu ~3e-3 << 0.185 threshold
static __device__ __forceinline__ float gelu_fast(float v) {
  float v2 = v * v;
  float u2 = v * (1.5957691216f + 0.0713548163f * v2);
  return v / (1.0f + __expf(-u2));
}

__global__ __launch_bounds__(256, 2) void fused_mlp_wavesolo(
    const float* __restrict__ x, const float* __restrict__ W1,
    const float* __restrict__ b1, const float* __restrict__ W2,
    const float* __restrict__ b2, float* __restrict__ out) {
  // Wlds: 2 layers x 2048 entries x 8 bf16. Entry e=(ks<<9)|(nt<<6)|lane holds
  // {W[ks*32+(lane>>4)*8+j][nt*16+(lane&15)]} -> frag read = contiguous
  // 1 KB/wave ds_read_b128 (conflict-free).
  __shared__ alignas(16) short Wlds[2 * 2048 * 8];          // 64 KB
  // Hs: per-wave private 16x128 bf16 scratch, XOR-swizzled rows.
  __shared__ alignas(16) char Hs[4][BT * Dd * 2];           // 16 KB

  const int tid  = threadIdx.x;
  const int lane = tid & 63;
  const int wid  = tid >> 6;
  const int lr   = lane & 15;
  const int lg   = lane >> 4;

  const int lh = blockIdx.x;
  const float* w1 = W1 + (size_t)lh * (Dd * Dd);
  const float* w2 = W2 + (size_t)lh * (Dd * Dd);

  const int row_base = wid * 128;          // this wave's 128 rows
  // per-lane x base: row (row_base + lr), k-offset lg*8
  const float* xa = x + ((size_t)(row_base + lr) * LH + lh) * Dd + lg * 8;

  // ---- issue tile-0 x loads first (in flight during W staging) ----
  float4 xf[8];
#pragma unroll
  for (int i = 0; i < 8; ++i)
    xf[i] = *(const float4*)(xa + (i >> 1) * 32 + (i & 1) * 4);

  // ---- cooperative W staging: 2048 entries/layer, 8 iters x 256 threads ----
#pragma unroll
  for (int it = 0; it < 16; ++it) {
    const int layer = it >> 3;
    const int e     = (it & 7) * 256 + tid;
    const int ks = e >> 9, nt = (e >> 6) & 7, lam = e & 63;
    const float* w = (layer ? w2 : w1) +
                     (size_t)(ks * 32 + (lam >> 4) * 8) * Dd + nt * 16 + (lam & 15);
    bf16x8 b;
#pragma unroll
    for (int j = 0; j < 8; ++j) b[j] = f2bf(w[j * Dd]);
    *(bf16x8*)((char*)Wlds + ((size_t)layer * 2048 + e) * 16) = b;
  }

  // biases for this lane's 8 columns (col = nt*16 + lr)
  float bb1[8], bb2[8];
#pragma unroll
  for (int nt = 0; nt < 8; ++nt) {
    bb1[nt] = b1[lh * Dd + nt * 16 + lr];
    bb2[nt] = b2[lh * Dd + nt * 16 + lr];
  }

  __syncthreads();   // W visible; the ONLY block-wide barrier

  const char* WL1 = (const char*)Wlds;
  const char* WL2 = (const char*)Wlds + 2048 * 16;
  char* Hb = Hs[wid];

  for (int t = 0; t < NTILE; ++t) {
    // prefetch next tile's x (full-tile distance: lands under ~2000 cyc of work)
    float4 xn[8];
    if (t + 1 < NTILE) {
#pragma unroll
      for (int i = 0; i < 8; ++i)
        xn[i] = *(const float4*)(xa + (size_t)(t + 1) * BT * XSTRIDE +
                                 (i >> 1) * 32 + (i & 1) * 4);
    }

    // ---------------- GEMM1: H = gelu(X @ W1 + b1) ----------------
    f32x4 acc[8];
#pragma unroll
    for (int nt = 0; nt < 8; ++nt) acc[nt] = (f32x4){bb1[nt], bb1[nt], bb1[nt], bb1[nt]};
#pragma unroll
    for (int ks = 0; ks < 4; ++ks) {
      const float4 lo = xf[ks * 2], hi = xf[ks * 2 + 1];
      bf16x8 a;
      a[0] = f2bf(lo.x); a[1] = f2bf(lo.y); a[2] = f2bf(lo.z); a[3] = f2bf(lo.w);
      a[4] = f2bf(hi.x); a[5] = f2bf(hi.y); a[6] = f2bf(hi.z); a[7] = f2bf(hi.w);
#pragma unroll
      for (int nt = 0; nt < 8; ++nt) {
        const bf16x8 wf = *(const bf16x8*)(WL1 + (size_t)(ks * 512 + nt * 64 + lane) * 16);
        acc[nt] = __builtin_amdgcn_mfma_f32_16x16x32_bf16(a, wf, acc[nt], 0, 0, 0);
      }
    }
#pragma unroll
    for (int i = 0; i < 8; ++i) xf[i] = xn[i];

    // GELU -> bf16 -> wave-private H (XOR-swizzled); per-wave lgkmcnt only
#pragma unroll
    for (int nt = 0; nt < 8; ++nt)
#pragma unroll
      for (int r = 0; r < 4; ++r) {
        const int rl  = lg * 4 + r;               // C/D row = (lane>>4)*4 + reg
        const int off = (rl * 256 + (nt * 16 + lr) * 2) ^ ((rl & 7) << 4);
        *(short*)(Hb + off) = f2bf(gelu_fast(acc[nt][r]));
      }

    // ---------------- GEMM2: out = H @ W2 + b2 ----------------
    f32x4 acc2[8];
#pragma unroll
    for (int nt = 0; nt < 8; ++nt) acc2[nt] = (f32x4){bb2[nt], bb2[nt], bb2[nt], bb2[nt]};
#pragma unroll
    for (int ks = 0; ks < 4; ++ks) {
      const int aoff = (lr * 256 + ks * 64 + lg * 16) ^ ((lr & 7) << 4);
      const bf16x8 aH = *(const bf16x8*)(Hb + aoff);
#pragma unroll
      for (int nt = 0; nt < 8; ++nt) {
        const bf16x8 wf = *(const bf16x8*)(WL2 + (size_t)(ks * 512 + nt * 64 + lane) * 16);
        acc2[nt] = __builtin_amdgcn_mfma_f32_16x16x32_bf16(aH, wf, acc2[nt], 0, 0, 0);
      }
    }

    // stores: 16-lane groups write 64 B contiguous; drain async (no barriers)
    {
      float* ob = out + ((size_t)(row_base + t * BT) * LH + lh) * Dd;
#pragma unroll
      for (int nt = 0; nt < 8; ++nt)
#pragma unroll
        for (int r = 0; r < 4; ++r)
          ob[(size_t)(lg * 4 + r) * XSTRIDE + nt * 16 + lr] = acc2[nt][r];
    }
  }
}

extern "C" void kernel_launch(void* const* d_in, const int* in_sizes, int n_in,
                              void* d_out, int out_size, void* d_ws, size_t ws_size,
                              hipStream_t stream) {
  (void)in_sizes; (void)n_in; (void)d_ws; (void)ws_size; (void)out_size;
  const float* x  = (const float*)d_in[0];
  const float* W1 = (const float*)d_in[1];
  const float* b1 = (const float*)d_in[2];
  const float* W2 = (const float*)d_in[3];
  const float* b2 = (const float*)d_in[4];
  float* out = (float*)d_out;
  fused_mlp_wavesolo<<<dim3(LH), dim3(256), 0, stream>>>(x, W1, b1, W2, b2, out);
}

// Round 15
// 153.335 us; speedup vs baseline: 3.4829x; 3.4829x over previous
//
#include <hip/hip_runtime.h>
#include <cstdint>
#include <cstddef>

// x[B=512, L=32, H=32, D=128]; per (l,h): Linear(128->128) -> GELU -> Linear(128->128)
// R15 = R11 structure (persistent-per-lh, DMA-staged x, W in regs, counted
// vmcnt) with a 4-buffer x pipeline staged 3 tiles ahead: continuous 32-48 KB
// DMA in flight per block (R9/R11 was a once-per-tile 32KB burst at ~50% duty
// cycle -> 3 TB/s). LDS stays 64 KB -> 2 blocks/CU -> R9's traffic-clean
// residency window (R13 proved 4 blocks/CU destroys the L3 credit).
#define LH      1024
#define Dd      128
#define BT      32            // batch rows per tile -> 16 KB f32 per buffer
#define NTILE   16            // 512 / 32
#define NBUF    4
#define XSTRIDE (LH * Dd)

typedef __attribute__((ext_vector_type(8))) short bf16x8;
typedef __attribute__((ext_vector_type(4))) float f32x4;
typedef const __attribute__((address_space(1))) uint32_t gu32;
typedef __attribute__((address_space(3))) uint32_t lu32;

static __device__ __forceinline__ short f2bf(float f) {
  return __builtin_bit_cast(short, (__bf16)f);
}

// tanh-form GELU as one sigmoid; |diff| vs erf-gelu ~3e-3 << 0.185 threshold
static __device__ __forceinline__ float gelu_fast(float v) {
  float v2 = v * v;
  float u2 = v * (1.5957691216f + 0.0713548163f * v2);
  return v / (1.0f + __expf(-u2));
}

// LDS-only barrier: ds ops drained; global loads/stores stay in flight.
#define BAR_LGKM() do {                                          \
  __builtin_amdgcn_sched_barrier(0);                             \
  asm volatile("s_waitcnt lgkmcnt(0)" ::: "memory");             \
  __builtin_amdgcn_s_barrier();                                  \
  __builtin_amdgcn_sched_barrier(0);                             \
} while (0)

// x-ready barrier: stage(t) proven done via in-order retire (m135).
// Newer-than-stage(t) ops at this point: stores(t-3..t-1) 3x16 + stage(t+1..
// t+3) 3x4 = 60 -> vmcnt(60) drains stage(t) exactly; stores stay in flight.
#define BAR_X() do {                                             \
  __builtin_amdgcn_sched_barrier(0);                             \
  asm volatile("s_waitcnt vmcnt(60) lgkmcnt(0)" ::: "memory");   \
  __builtin_amdgcn_s_barrier();                                  \
  __builtin_amdgcn_sched_barrier(0);                             \
} while (0)

__global__ __launch_bounds__(256, 2) void fused_mlp_persist(
    const float* __restrict__ x, const float* __restrict__ W1,
    const float* __restrict__ b1, const float* __restrict__ W2,
    const float* __restrict__ b2, float* __restrict__ out) {
  // 4 rotating buffers of 16 KB. Each: x f32 [32 rows][32 chunks of 16B],
  // chunk-index XOR-swizzled on the GLOBAL source addr (global_load_lds
  // writes LDS linearly, m104/m173). H bf16 [32][128] (8 KB) overlays bytes
  // 0..8K of the CURRENT buffer after GEMM1's reads are barrier-complete.
  __shared__ alignas(16) char smem[NBUF][BT * Dd * 4];   // 64 KB

  const int tid  = threadIdx.x;
  const int lane = tid & 63;
  const int wid  = tid >> 6;     // 4 waves, each owns 32 N-columns
  const int lr   = lane & 15;
  const int lg   = lane >> 4;

  const int lh = blockIdx.x;     // W reuse is intra-block
  const int n0 = wid * 32;

  const float* w1  = W1 + (size_t)lh * (Dd * Dd);
  const float* w2  = W2 + (size_t)lh * (Dd * Dd);
  const float* xlh = x   + (size_t)lh * Dd;
  float*       olh = out + (size_t)lh * Dd;

  // stage tile t into buffer buf: 4 DMA issues/wave, 16 KB/block
  auto stage = [&](int t, int buf) {
#pragma unroll
    for (int i = 0; i < 4; ++i) {
      const int slot = wid * 4 + i;          // wave-uniform 1KB LDS slot
      const int row  = slot * 2 + (lane >> 5);
      const int cp   = lane & 31;            // chunk position in LDS
      const int c    = cp ^ (row & 15);      // global chunk (bijective swz)
      const float* g = xlh + (size_t)(t * BT + row) * XSTRIDE + c * 4;
      __builtin_amdgcn_global_load_lds((gu32*)g,
                                       (lu32*)(smem[buf] + slot * 1024),
                                       16, 0, 0);
    }
  };

  // ---- prologue: stage tiles 0..2 (48 KB in flight); gather ALL W
  // fragments to regs under the DMA flight; biases.
  stage(0, 0);
  stage(1, 1);
  stage(2, 2);

  bf16x8 bw1[4][2], bw2[4][2];
#pragma unroll
  for (int ks = 0; ks < 4; ++ks)
#pragma unroll
    for (int nt = 0; nt < 2; ++nt) {
      const float* p1 = w1 + (size_t)(ks * 32 + lg * 8) * Dd + n0 + nt * 16 + lr;
      const float* p2 = w2 + (size_t)(ks * 32 + lg * 8) * Dd + n0 + nt * 16 + lr;
      bf16x8 a, b;
#pragma unroll
      for (int j = 0; j < 8; ++j) { a[j] = f2bf(p1[j * Dd]); b[j] = f2bf(p2[j * Dd]); }
      bw1[ks][nt] = a;
      bw2[ks][nt] = b;
    }

  const float bb1_0 = b1[lh * Dd + n0 + lr];
  const float bb1_1 = b1[lh * Dd + n0 + 16 + lr];
  const float bb2_0 = b2[lh * Dd + n0 + lr];
  const float bb2_1 = b2[lh * Dd + n0 + 16 + lr];

  // prologue barrier: full drain (stages 0-2 + W loads), once per block
  __builtin_amdgcn_sched_barrier(0);
  asm volatile("s_waitcnt vmcnt(0) lgkmcnt(0)" ::: "memory");
  __builtin_amdgcn_s_barrier();
  __builtin_amdgcn_sched_barrier(0);

  for (int t = 0; t < NTILE; ++t) {
    const int cur = t & (NBUF - 1);

    // keep the pipe 3 deep; buf (t+3)&3 proven free by iter t-1's end barrier
    if (t + 3 < NTILE) stage(t + 3, (t + 3) & (NBUF - 1));

    BAR_X();   // x[t] visible in smem[cur]; stores stay in flight

    // ---------------- GEMM1: H = gelu(X @ W1 + b1) ----------------
    f32x4 acc[2][2];
#pragma unroll
    for (int mt = 0; mt < 2; ++mt) {
      acc[mt][0] = (f32x4){bb1_0, bb1_0, bb1_0, bb1_0};
      acc[mt][1] = (f32x4){bb1_1, bb1_1, bb1_1, bb1_1};
    }
#pragma unroll
    for (int ks = 0; ks < 4; ++ks) {
      bf16x8 af[2];
#pragma unroll
      for (int mt = 0; mt < 2; ++mt) {
        const int row = mt * 16 + lr;
        const int c0  = ks * 8 + lg * 2;
        const int m   = row & 15;
        const float4 lo = *(const float4*)(smem[cur] + row * 512 + ((c0)     ^ m) * 16);
        const float4 hi = *(const float4*)(smem[cur] + row * 512 + ((c0 + 1) ^ m) * 16);
        bf16x8 a;
        a[0] = f2bf(lo.x); a[1] = f2bf(lo.y); a[2] = f2bf(lo.z); a[3] = f2bf(lo.w);
        a[4] = f2bf(hi.x); a[5] = f2bf(hi.y); a[6] = f2bf(hi.z); a[7] = f2bf(hi.w);
        af[mt] = a;
      }
#pragma unroll
      for (int mt = 0; mt < 2; ++mt)
#pragma unroll
        for (int nt = 0; nt < 2; ++nt)
          acc[mt][nt] = __builtin_amdgcn_mfma_f32_16x16x32_bf16(af[mt], bw1[ks][nt], acc[mt][nt], 0, 0, 0);
    }

    // GELU in regs before the barrier
    short hv[2][2][4];
#pragma unroll
    for (int mt = 0; mt < 2; ++mt)
#pragma unroll
      for (int nt = 0; nt < 2; ++nt)
#pragma unroll
        for (int r = 0; r < 4; ++r)
          hv[mt][nt][r] = f2bf(gelu_fast(acc[mt][nt][r]));

    BAR_LGKM();   // all waves done reading x[cur]

#pragma unroll
    for (int mt = 0; mt < 2; ++mt)
#pragma unroll
      for (int nt = 0; nt < 2; ++nt) {
        const int e = n0 + nt * 16 + lr;
#pragma unroll
        for (int r = 0; r < 4; ++r) {
          const int b = mt * 16 + lg * 4 + r;   // C/D row = (lane>>4)*4 + reg
          const int off = (b * 256 + e * 2) ^ ((b & 7) << 4);
          *(short*)(smem[cur] + off) = hv[mt][nt][r];
        }
      }

    BAR_LGKM();   // H visible

    // ---------------- GEMM2: out = H @ W2 + b2 (W2 in regs) ----------
    f32x4 acc2[2][2];
#pragma unroll
    for (int mt = 0; mt < 2; ++mt) {
      acc2[mt][0] = (f32x4){bb2_0, bb2_0, bb2_0, bb2_0};
      acc2[mt][1] = (f32x4){bb2_1, bb2_1, bb2_1, bb2_1};
    }
#pragma unroll
    for (int ks = 0; ks < 4; ++ks) {
      const int k2 = (ks * 32 + lg * 8) * 2;   // byte offset of 16B H granule
#pragma unroll
      for (int mt = 0; mt < 2; ++mt) {
        const int b = mt * 16 + lr;
        const int off = (b * 256 + k2) ^ ((b & 7) << 4);
        bf16x8 a = *(const bf16x8*)(smem[cur] + off);
#pragma unroll
        for (int nt = 0; nt < 2; ++nt)
          acc2[mt][nt] = __builtin_amdgcn_mfma_f32_16x16x32_bf16(a, bw2[ks][nt], acc2[mt][nt], 0, 0, 0);
      }
    }

    // epilogue: 16 f32 stores, async drain (accounted by BAR_X's vmcnt(60))
    {
      float* ob = olh + (size_t)(t * BT) * XSTRIDE;
#pragma unroll
      for (int mt = 0; mt < 2; ++mt)
#pragma unroll
        for (int nt = 0; nt < 2; ++nt) {
          const int e = n0 + nt * 16 + lr;
#pragma unroll
          for (int r = 0; r < 4; ++r) {
            const int b = mt * 16 + lg * 4 + r;
            ob[(size_t)b * XSTRIDE + e] = acc2[mt][nt][r];
          }
        }
    }

    // end-of-iter: all waves past GEMM2's H reads of smem[cur] -> next iter
    // may stage over buf (t+4)&3 == cur. LDS-only wait; stores keep flying.
    BAR_LGKM();
  }
}

extern "C" void kernel_launch(void* const* d_in, const int* in_sizes, int n_in,
                              void* d_out, int out_size, void* d_ws, size_t ws_size,
                              hipStream_t stream) {
  (void)in_sizes; (void)n_in; (void)d_ws; (void)ws_size; (void)out_size;
  const float* x  = (const float*)d_in[0];
  const float* W1 = (const float*)d_in[1];
  const float* b1 = (const float*)d_in[2];
  const float* W2 = (const float*)d_in[3];
  const float* b2 = (const float*)d_in[4];
  float* out = (float*)d_out;
  fused_mlp_persist<<<dim3(LH), dim3(256), 0, stream>>>(x, W1, b1, W2, b2, out);
}